// Round 16
// baseline (222.446 us; speedup 1.0000x reference)
//
#include <hip/hip_runtime.h>
#include <hip/hip_bf16.h>
#include <cstddef>
#include <cstdint>

#define NROWS 8192
#define LOG2E 1.4426950408889634f

typedef __attribute__((ext_vector_type(8))) short bf16x8;
typedef __attribute__((ext_vector_type(4))) float f32x4;

#define EXP2(x) __builtin_amdgcn_exp2f(x)

__device__ __forceinline__ short f2bf(float f) {
  unsigned u = __float_as_uint(f);
  u += 0x7fffu + ((u >> 16) & 1u);   // RNE
  return (short)(u >> 16);
}
__device__ __forceinline__ float leaky_f(float v) { return fmaxf(v, 0.1f * v); }

union BFPair { __hip_bfloat162 h; unsigned u; };
__device__ __forceinline__ unsigned pack2(float a, float b) {
  BFPair p;
  p.h = __float22bfloat162_rn(make_float2(a, b));  // v_cvt_pk_bf16_f32
  return p.u;
}
__device__ __forceinline__ f32x4 ntload4(const float* p) {
  return __builtin_nontemporal_load((const f32x4*)p);
}

// ---------------- Kernel 1: MLP encoder: x[8192,256] -> x2, s(prescaled), sq, x2bfT --
extern "C" __global__ void __launch_bounds__(256)
encoder_kernel(const float* __restrict__ x, const float* __restrict__ W10,
               const float* __restrict__ b10, const float* __restrict__ W11,
               const float* __restrict__ b11, const float* __restrict__ avec,
               float* __restrict__ x2, float* __restrict__ sarr,
               float* __restrict__ sqarr, short* __restrict__ x2bfT) {
  __shared__ float xr[4][256];
  __shared__ float h1[4][128];
  const int t = threadIdx.x;
  const int r0 = blockIdx.x * 4;
#pragma unroll
  for (int r = 0; r < 4; ++r) xr[r][t] = x[(size_t)(r0 + r) * 256 + t];
  __syncthreads();
  if (t < 128) {
    float acc[4];
    const float b = b10[t];
#pragma unroll
    for (int r = 0; r < 4; ++r) acc[r] = b;
    const float* wrow = W10 + t * 256;
    for (int c = 0; c < 256; c += 4) {
      const float4 wv = *(const float4*)(wrow + c);
#pragma unroll
      for (int r = 0; r < 4; ++r) {
        acc[r] = fmaf(wv.x, xr[r][c], acc[r]);
        acc[r] = fmaf(wv.y, xr[r][c + 1], acc[r]);
        acc[r] = fmaf(wv.z, xr[r][c + 2], acc[r]);
        acc[r] = fmaf(wv.w, xr[r][c + 3], acc[r]);
      }
    }
#pragma unroll
    for (int r = 0; r < 4; ++r) h1[r][t] = leaky_f(acc[r]);
  }
  __syncthreads();
  if (t < 64) {
    float acc[4];
    const float b = b11[t];
#pragma unroll
    for (int r = 0; r < 4; ++r) acc[r] = b;
    const float* wrow = W11 + t * 128;
    for (int c = 0; c < 128; c += 4) {
      const float4 wv = *(const float4*)(wrow + c);
#pragma unroll
      for (int r = 0; r < 4; ++r) {
        acc[r] = fmaf(wv.x, h1[r][c], acc[r]);
        acc[r] = fmaf(wv.y, h1[r][c + 1], acc[r]);
        acc[r] = fmaf(wv.z, h1[r][c + 2], acc[r]);
        acc[r] = fmaf(wv.w, h1[r][c + 3], acc[r]);
      }
    }
    const float av = avec[t];
#pragma unroll
    for (int r = 0; r < 4; ++r) {
      const float v = leaky_f(acc[r]);
      x2[(size_t)(r0 + r) * 64 + t] = v;
      x2bfT[(size_t)t * NROWS + r0 + r] = f2bf(v);
      float ps = v * av, pq = v * v;
#pragma unroll
      for (int off = 1; off < 64; off <<= 1) {
        ps += __shfl_xor(ps, off);
        pq += __shfl_xor(pq, off);
      }
      if (t == 0) {
        sarr[r0 + r] = ps * LOG2E;          // exp(leaky(d)) = exp2(leaky(d*log2e))
        sqarr[r0 + r] = pq * (1.0f / 64.0f);
      }
    }
  }
}

// ---------------- Kernel 1b: B fragments (16x16x32 layout, contiguous) --------------
// Bfrag[S][nf][lane][8]: x2^T[n = nf*16 + (lane&15)][k = S*32 + (lane>>4)*8 + e]
extern "C" __global__ void __launch_bounds__(256)
prep16_kernel(const short* __restrict__ x2bfT, short* __restrict__ Bfrag) {
  const int S = blockIdx.x;           // 256 k-groups of 32
  const int t = threadIdx.x;
  const int nf = t >> 6, l = t & 63;
  const bf16x8 v = *(const bf16x8*)(x2bfT + (size_t)(nf * 16 + (l & 15)) * NROWS
                                    + S * 32 + (l >> 4) * 8);
  *(bf16x8*)(Bfrag + ((size_t)S * 4 + nf) * 512 + l * 8) = v;
}

// ---------------- Kernel 2: fused dense-sweep + MFMA (window-permuted convbench) ----
// 1024 blocks x 512 thr. Wave w of block b handles chunks {b + w*1024 + k*8192}:
// instantaneous chip-wide set == convbench's dense 8MB sliding window (validated),
// only wave assignment permuted. Block: cc = b&31 fixed; per k, 8 rows spaced 32.
// E: 1KB nt row-read, exp2 (validated math), exact fp32 scalars, bf16 -> LDS A-frag
// (rows 8..15 zero). M: waves 0..3, nf=w: 8 MFMAs vs REGISTER-hoisted B-frags
// (k-invariant!), 2KB C-partial per (b,k) to dense sliding slots. No tiled A access.
extern "C" __global__ void __launch_bounds__(512)
fused_sweep2_kernel(const float* __restrict__ A, const float* __restrict__ sarr,
                    const float* __restrict__ sqarr, const short* __restrict__ Bfrag,
                    float* __restrict__ P, float* __restrict__ Ssc) {
  __shared__ __attribute__((aligned(16))) short fragA[8 * 64 * 8];   // [s][lam][e] 8KB
  __shared__ __attribute__((aligned(16))) float sjbuf[256];
  __shared__ __attribute__((aligned(16))) float sqbuf[256];
  const int t = threadIdx.x, l = t & 63;
  const int w = t >> 6;                 // 0..7
  const int b = blockIdx.x;
  const int cc = b & 31;                // fixed col-chunk

  // zero fragA once: rows 8..15 remain zero for the whole kernel
  for (int z = t; z < 2048; z += 512) ((int*)fragA)[z] = 0;
  if (t < 256) { sjbuf[t] = sarr[cc * 256 + t]; sqbuf[t] = sqarr[cc * 256 + t]; }
  __syncthreads();

  // E-phase constants: lane l covers j = cc*256 + l*4 .. +4 of its wave's row
  const int s_l = l >> 3;
  const int lam_e = w + ((l & 7) >> 1) * 16;
  short* ewp = fragA + ((s_l * 64 + lam_e) * 8) + (l & 1) * 4;
  const f32x4 sj = *(const f32x4*)(sjbuf + l * 4);
  const f32x4 sq = *(const f32x4*)(sqbuf + l * 4);

  // M-phase: hoist the k-invariant B fragments (Sg = cc*8 + s, nf = w) into regs
  bf16x8 breg[8];
  if (w < 4) {
    const short* bp = Bfrag + (((size_t)(cc * 8) * 4 + w) * 512) + l * 8;
#pragma unroll
    for (int s = 0; s < 8; ++s) breg[s] = *(const bf16x8*)(bp + (size_t)s * 2048);
  }

#pragma unroll 1
  for (int k = 0; k < 32; ++k) {
    const int chunk = b + w * 1024 + k * 8192;
    const int i = (b >> 5) + w * 32 + k * 256;
    const float sif = sarr[i];
    const f32x4 a4 = ntload4(A + (size_t)chunk * 256 + l * 4);
    const float d0 = sif - sj[0], d1 = sif - sj[1];
    const float d2 = sif - sj[2], d3 = sif - sj[3];
    const float r0 = EXP2(fmaxf(d0, 0.1f * d0)) * a4[0];
    const float r1 = EXP2(fmaxf(d1, 0.1f * d1)) * a4[1];
    const float r2 = EXP2(fmaxf(d2, 0.1f * d2)) * a4[2];
    const float r3 = EXP2(fmaxf(d3, 0.1f * d3)) * a4[3];
    uint2 pk;
    pk.x = pack2(r0, r1);
    pk.y = pack2(r2, r3);
    *(uint2*)ewp = pk;
    float a = (r0 + r1) + (r2 + r3);
    float bb = fmaf(r0, r0, fmaf(r1, r1, fmaf(r2, r2, r3 * r3)));
    float c = fmaf(r0, sq[0], fmaf(r1, sq[1], fmaf(r2, sq[2], r3 * sq[3])));
#pragma unroll
    for (int off = 1; off < 64; off <<= 1) {
      a += __shfl_xor(a, off);
      bb += __shfl_xor(bb, off);
      c += __shfl_xor(c, off);
    }
    if (l == 0) {
      float* sp = Ssc + ((size_t)(k * 1024 + b)) * 32 + w * 4;
      sp[0] = a; sp[1] = bb; sp[2] = c; sp[3] = 0.f;
    }
    __syncthreads();   // E-writes visible
    if (w < 4) {
      f32x4 acc = {0.f, 0.f, 0.f, 0.f};
#pragma unroll
      for (int s = 0; s < 8; ++s) {
        const bf16x8 ar = *(const bf16x8*)(fragA + (s * 64 + l) * 8);
        acc = __builtin_amdgcn_mfma_f32_16x16x32_bf16(ar, breg[s], acc, 0, 0, 0);
      }
      if (l < 32)
        *(f32x4*)(P + ((size_t)(k * 1024 + b)) * 512 + (w * 32 + l) * 4) = acc;
    }
    __syncthreads();   // M-reads done before next E overwrites fragA
  }
}

// ---------------- Kernel 2b: fold 32 cc-partials (64KB contiguous per block) --------
// grid 1024: k = bid>>5, r5 = bid&31. Record (b,k) holds rows {r5 + fr*32 + k*256}.
extern "C" __global__ void __launch_bounds__(256)
reduce_kernel(const float* __restrict__ P, const float* __restrict__ Ssc,
              float* __restrict__ y, float* __restrict__ rs,
              float* __restrict__ ss, float* __restrict__ ws) {
  const int k = blockIdx.x >> 5, r5 = blockIdx.x & 31;
  const int t = threadIdx.x;
  const float* base = P + ((size_t)(k * 1024 + r5 * 32)) * 512;
  float s0 = 0.f, s1 = 0.f;
#pragma unroll 8
  for (int cc = 0; cc < 32; ++cc) {
    const float2 v = *(const float2*)(base + (size_t)cc * 512 + t * 2);
    s0 += v.x; s1 += v.y;
  }
  {
    const int f = t * 2;
    const int nf = f >> 7, lam = (f >> 2) & 31, reg = f & 3;
    const int fr = (lam >> 4) * 4 + reg;
    y[(size_t)(r5 + fr * 32 + k * 256) * 64 + nf * 16 + (lam & 15)] = s0;
  }
  {
    const int f = t * 2 + 1;
    const int nf = f >> 7, lam = (f >> 2) & 31, reg = f & 3;
    const int fr = (lam >> 4) * 4 + reg;
    y[(size_t)(r5 + fr * 32 + k * 256) * 64 + nf * 16 + (lam & 15)] = s1;
  }
  if (t < 32) {
    const int w = t >> 2, comp = t & 3;
    const float* sb = Ssc + ((size_t)(k * 1024 + r5 * 32)) * 32 + w * 4 + comp;
    float acc = 0.f;
#pragma unroll 8
    for (int cc = 0; cc < 32; ++cc) acc += sb[(size_t)cc * 32];
    const int i = r5 + w * 32 + k * 256;
    if (comp == 0) rs[i] = acc;
    else if (comp == 1) ss[i] = acc;
    else if (comp == 2) ws[i] = acc;
  }
}

// ---------------- Kernel 3: GNN layer + head, per-row losses ------------------------
extern "C" __global__ void __launch_bounds__(256)
finish_kernel(const float* __restrict__ x2, const float* __restrict__ sqarr,
              const float* __restrict__ yp, const float* __restrict__ rs,
              const float* __restrict__ ss, const float* __restrict__ ws,
              const float* __restrict__ Wg, const float* __restrict__ bg,
              const float* __restrict__ W2, const float* __restrict__ b2,
              float* __restrict__ outp, float* __restrict__ l1c, float* __restrict__ l2c) {
  __shared__ float hbuf[4][64];
  __shared__ float gbuf[4][64];
  const int t = threadIdx.x;
  const int w = t >> 6, lane = t & 63;
  const int i = blockIdx.x * 4 + w;

  const float yv = yp[(size_t)i * 64 + lane];
  const float rowsum = rs[i], sumsq = ss[i], wsq = ws[i];
  const float inv = 1.0f / rowsum;
  hbuf[w][lane] = yv * inv;
  const float xv = x2[(size_t)i * 64 + lane];
  float xy = xv * yv;
#pragma unroll
  for (int off = 1; off < 64; off <<= 1) xy += __shfl_xor(xy, off);
  if (lane == 0) {
    l1c[i] = sqarr[i] + (wsq - (2.0f / 64.0f) * xy) * inv;
    l2c[i] = sumsq * inv * inv;
  }
  __syncthreads();
  float accg = bg[lane];
  {
    const float* wrow = Wg + lane * 64;
#pragma unroll 4
    for (int d = 0; d < 64; ++d) accg = fmaf(wrow[d], hbuf[w][d], accg);
  }
  gbuf[w][lane] = leaky_f(accg);
  __syncthreads();
  if (lane < 32) {
    float acco = b2[lane];
    const float* wrow = W2 + lane * 64;
#pragma unroll 4
    for (int d = 0; d < 64; ++d) acco = fmaf(wrow[d], gbuf[w][d], acco);
    outp[(size_t)i * 32 + lane] = acco;
  }
}

// ---------------- Kernel 4: scalar loss reduction -----------------------------------
extern "C" __global__ void __launch_bounds__(256)
loss_kernel(const float* __restrict__ l1c, const float* __restrict__ l2c,
            float* __restrict__ outp) {
  __shared__ float s1[256], s2[256];
  const int t = threadIdx.x;
  float a1 = 0.f, a2 = 0.f;
  for (int i = t * 4; i < NROWS; i += 1024) {
    const float4 v1 = *(const float4*)(l1c + i);
    const float4 v2 = *(const float4*)(l2c + i);
    a1 += (v1.x + v1.y) + (v1.z + v1.w);
    a2 += (v2.x + v2.y) + (v2.z + v2.w);
  }
  s1[t] = a1; s2[t] = a2;
  __syncthreads();
  for (int off = 128; off > 0; off >>= 1) {
    if (t < off) { s1[t] += s1[t + off]; s2[t] += s2[t + off]; }
    __syncthreads();
  }
  if (t == 0) {
    const float scale = 1.0f / ((float)NROWS * (float)NROWS);
    outp[NROWS * 32] = s1[0] * scale;
    outp[NROWS * 32 + 1] = s2[0] * scale;
  }
}

// ---------------- launch ------------------------------------------------------------
extern "C" void kernel_launch(void* const* d_in, const int* in_sizes, int n_in,
                              void* d_out, int out_size, void* d_ws, size_t ws_size,
                              hipStream_t stream) {
  const float* x   = (const float*)d_in[0];
  const float* A   = (const float*)d_in[1];
  const float* W10 = (const float*)d_in[2];
  const float* b10 = (const float*)d_in[3];
  const float* W11 = (const float*)d_in[4];
  const float* b11 = (const float*)d_in[5];
  const float* av  = (const float*)d_in[6];
  const float* Wg  = (const float*)d_in[7];
  const float* bg  = (const float*)d_in[8];
  const float* W2  = (const float*)d_in[9];
  const float* b2  = (const float*)d_in[10];
  float* out = (float*)d_out;

  // workspace layout (~75 MB; >=175 MB proven available)
  float* ws_f  = (float*)d_ws;
  float* x2    = ws_f;                                 // N*64
  float* sarr  = x2 + (size_t)NROWS * 64;              // N (prescaled by log2e)
  float* sqarr = sarr + NROWS;                         // N
  float* l1c   = sqarr + NROWS;                        // N
  float* l2c   = l1c + NROWS;                          // N
  float* rs    = l2c + NROWS;                          // N
  float* ssum  = rs + NROWS;                           // N
  float* wsq   = ssum + NROWS;                         // N
  float* y     = wsq + NROWS;                          // N*64
  float* P     = y + (size_t)NROWS * 64;               // 32*1024*512 = 16.8M floats (64MB)
  float* Ssc   = P + (size_t)32 * 1024 * 512;          // 32*1024*32 = 1M floats (4MB)
  short* x2bfT = (short*)(Ssc + (size_t)32 * 1024 * 32);   // N*64 bf16
  short* Bfrag = x2bfT + (size_t)NROWS * 64;           // 256*2048 bf16 (1MB)

  hipLaunchKernelGGL(encoder_kernel, dim3(2048), dim3(256), 0, stream,
                     x, W10, b10, W11, b11, av, x2, sarr, sqarr, x2bfT);
  hipLaunchKernelGGL(prep16_kernel, dim3(256), dim3(256), 0, stream, x2bfT, Bfrag);
  hipLaunchKernelGGL(fused_sweep2_kernel, dim3(1024), dim3(512), 0, stream,
                     A, sarr, sqarr, Bfrag, P, Ssc);
  hipLaunchKernelGGL(reduce_kernel, dim3(1024), dim3(256), 0, stream,
                     P, Ssc, y, rs, ssum, wsq);
  hipLaunchKernelGGL(finish_kernel, dim3(2048), dim3(256), 0, stream,
                     x2, sqarr, y, rs, ssum, wsq, Wg, bg, W2, b2, out, l1c, l2c);
  hipLaunchKernelGGL(loss_kernel, dim3(1), dim3(256), 0, stream, l1c, l2c, out);
}